// Round 9
// baseline (14857.245 us; speedup 1.0000x reference)
//
#include <hip/hip_runtime.h>

#define NE    16384
#define NTOT  17408
#define NPE   524288.0f

/* workspace layout (bytes); demand = 1MB + 64MB */
#define O_STATS1   0          /* [32][128] f32 */
#define O_STATS2   16384
#define O_DEG      32768      /* f32[1024] */
#define O_CNT      36864      /* i32[1024] */
#define ZERO_WORDS 10240      /* zero first 40960 bytes */
#define O_DINV     40960
#define O_ROWSTART 45056      /* i32[1025] */
#define O_FILL     49216
#define O_BNP1     53312      /* f32[128] */
#define O_BNP2     53824
#define O_FLAG     54400      /* int: 1 if external tensors are fp32 */
#define O_CSR      65536      /* int2[17408] */
#define O_BIG      1048576    /* bf16 33.5M = 64MB */

static __device__ __forceinline__ float bf2f(unsigned short u) {
  return __uint_as_float(((unsigned)u) << 16);
}
static __device__ __forceinline__ unsigned short f2bf(float f) {
  unsigned u = __float_as_uint(f);
  return (unsigned short)((u + 0x7fffu + ((u >> 16) & 1u)) >> 16);
}
/* dual-dtype load of external tensor element i */
static __device__ __forceinline__ float ldx(const void* p, int isf, long long i) {
  return isf ? ((const float*)p)[i] : bf2f(((const unsigned short*)p)[i]);
}

__global__ void STGCNBlock_90417651516131_kernel() {}

__global__ void stg_zero(float* p) {
  int i = blockIdx.x * 256 + threadIdx.x;
  if (i < ZERO_WORDS) p[i] = 0.f;
}

/* detect external dtype: bf16 array -> even u16s have plausible bf16 exponents */
__global__ void stg_detect(const void* x, int* flag) {
  __shared__ int cnt;
  if (threadIdx.x == 0) cnt = 0;
  __syncthreads();
  const unsigned short* u = (const unsigned short*)x;
  unsigned short v = u[threadIdx.x * 2];
  int e = (v >> 7) & 0xFF;
  if (v == 0 || (e >= 100 && e <= 140)) atomicAdd(&cnt, 1);
  __syncthreads();
  if (threadIdx.x == 0) flag[0] = (cnt > 128) ? 0 : 1;
}

/* conv 1x9 over t + bias; layouts [b][c][n][t]; BN stats (bucketed).
   inext=1: `in` is an external tensor (dtype per flag); 0: bf16 scratch. */
__global__ void stg_conv(const void* in, int inext, const void* w,
                         const void* bias, unsigned short* out,
                         float* stats, const int* flg) {
  __shared__ float rs[256], rq[256];
  const int isf = flg[0];
  const int inf = inext ? isf : 0;
  long long id = (long long)blockIdx.x * 256 + threadIdx.x;
  int t = (int)(id & 63);
  int n = (int)((id >> 6) & 1023);
  int c = (int)((id >> 16) & 63);
  int b = (int)(id >> 22);
  long long xb = (long long)b * 4194304 + n * 64;
  float acc = ldx(bias, isf, c);
  for (int ci = 0; ci < 64; ci++) {
    long long xp = xb + (long long)ci * 65536;
    long long wp = (long long)(c * 64 + ci) * 9;
    for (int k = 0; k < 9; k++) {
      int tt = t + k - 4;
      if (tt >= 0 && tt < 64)
        acc = fmaf(ldx(in, inf, xp + tt), ldx(w, isf, wp + k), acc);
    }
  }
  int tid = threadIdx.x;
  rs[tid] = acc; rq[tid] = acc * acc;
  __syncthreads();
  for (int off = 128; off > 0; off >>= 1) {
    if (tid < off) { rs[tid] += rs[tid + off]; rq[tid] += rq[tid + off]; }
    __syncthreads();
  }
  if (tid == 0) {
    float* st = stats + (blockIdx.x & 31) * 128;
    atomicAdd(&st[c], rs[0]);
    atomicAdd(&st[64 + c], rq[0]);
  }
  out[id] = f2bf(acc);
}

__global__ void stg_deg(const int* ei, const void* ew,
                        float* deg, int* cnt, const int* flg) {
  const int isf = flg[0];
  int e = blockIdx.x * 256 + threadIdx.x;
  if (e < NE) {
    int c = ei[NE + e];
    atomicAdd(&deg[c], ldx(ew, isf, e));
    atomicAdd(&cnt[c], 1);
  } else if (e < NTOT) {
    int nn = e - NE;
    atomicAdd(&deg[nn], 1.0f);
    atomicAdd(&cnt[nn], 1);
  }
}

__global__ void stg_scan(const float* deg, float* dinv, const int* cnt,
                         int* rowstart, int* fillpos) {
  __shared__ int sb[1024];
  int t = threadIdx.x;
  float d = deg[t];
  dinv[t] = d > 0.f ? rsqrtf(d) : 0.f;
  int v = cnt[t];
  sb[t] = v;
  __syncthreads();
  for (int off = 1; off < 1024; off <<= 1) {
    int add = (t >= off) ? sb[t - off] : 0;
    __syncthreads();
    sb[t] += add;
    __syncthreads();
  }
  if (t == 0) rowstart[0] = 0;
  rowstart[t + 1] = sb[t];
  fillpos[t] = sb[t] - v;
}

__global__ void stg_fill(const int* ei, const void* ew,
                         const float* dinv, int* fillpos, int2* csr,
                         const int* flg) {
  const int isf = flg[0];
  int e = blockIdx.x * 256 + threadIdx.x;
  if (e < NTOT) {
    int r, c; float wv;
    if (e < NE) { r = ei[e]; c = ei[NE + e]; wv = ldx(ew, isf, e); }
    else        { r = c = e - NE; wv = 1.f; }
    float norm = dinv[r] * wv * dinv[c];
    int pos = atomicAdd(&fillpos[c], 1);
    csr[pos] = make_int2(r, __float_as_int(norm));
  }
}

__global__ void stg_bnparam(const float* buckets, const void* g,
                            const void* be, float* bnp, const int* flg) {
  const int isf = flg[0];
  int c = threadIdx.x;
  float s = 0.f, ss = 0.f;
  for (int k = 0; k < 32; k++) { s += buckets[k * 128 + c]; ss += buckets[k * 128 + 64 + c]; }
  float m = s / NPE;
  float v = ss / NPE - m * m;
  float sc = ldx(g, isf, c) * rsqrtf(v + 1e-5f);
  bnp[c] = sc;
  bnp[64 + c] = ldx(be, isf, c) - m * sc;
}

/* BN1+ReLU+linear: h[b][d][n][t] = sum_c relu(bn(y[b][c][n][t])) * gw[c][d] */
__global__ void stg_linear(const unsigned short* y, const float* bnp,
                           const void* gw, unsigned short* hl, const int* flg) {
  const int isf = flg[0];
  long long id = (long long)blockIdx.x * 256 + threadIdx.x;
  int nt = (int)(id & 65535);
  int d = (int)((id >> 16) & 63);
  int b = (int)(id >> 22);
  const unsigned short* yb = y + (long long)b * 4194304 + nt;
  float acc = 0.f;
  for (int c = 0; c < 64; c++) {
    float v = fmaxf(fmaf(bf2f(yb[(long long)c * 65536]), bnp[c], bnp[64 + c]), 0.f);
    acc = fmaf(v, ldx(gw, isf, c * 64 + d), acc);
  }
  hl[id] = f2bf(acc);
}

/* aggregation: o[b][c][n][t] = relu(gb[c] + sum_{e: col=n} hl[b][c][row_e][t]*norm_e) */
__global__ void stg_agg(const unsigned short* hl, const int2* csr,
                        const int* rowstart, const void* gb,
                        unsigned short* o, const int* flg) {
  const int isf = flg[0];
  long long id = (long long)blockIdx.x * 256 + threadIdx.x;
  int t = (int)(id & 63);
  int n = (int)((id >> 6) & 1023);
  int c = (int)((id >> 16) & 63);
  int b = (int)(id >> 22);
  const unsigned short* base = hl + (long long)b * 4194304 + (long long)c * 65536 + t;
  float acc = 0.f;
  int s = rowstart[n], e1 = rowstart[n + 1];
  for (int e = s; e < e1; e++) {
    int2 p = csr[e];
    acc = fmaf(bf2f(base[p.x * 64]), __int_as_float(p.y), acc);
  }
  o[id] = f2bf(fmaxf(acc + ldx(gb, isf, c), 0.f));
}

/* BN2 + ReLU + residual; output dtype follows detected external dtype */
__global__ void stg_final(const unsigned short* y2, const float* bnp,
                          const void* x, void* out, const int* flg) {
  const int isf = flg[0];
  long long id = (long long)blockIdx.x * 256 + threadIdx.x;
  int c = (int)((id >> 16) & 63);
  float v = fmaxf(fmaf(bf2f(y2[id]), bnp[c], bnp[64 + c]), 0.f);
  float r = v + ldx(x, isf, id);
  if (isf) ((float*)out)[id] = r;
  else     ((unsigned short*)out)[id] = f2bf(r);
}

extern "C" void kernel_launch(void* const* d_in, const int* in_sizes, int n_in,
                              void* d_out, int out_size, void* d_ws, size_t ws_size,
                              hipStream_t stream) {
  (void)in_sizes; (void)n_in; (void)out_size; (void)ws_size;
  const void* x   = d_in[0];
  const int*  ei  = (const int*)d_in[1];
  const void* ew  = d_in[2];
  const void* w1  = d_in[3];
  const void* b1  = d_in[4];
  const void* g1  = d_in[5];
  const void* be1 = d_in[6];
  const void* gw  = d_in[7];
  const void* gb  = d_in[8];
  const void* w2  = d_in[9];
  const void* b2  = d_in[10];
  const void* g2  = d_in[11];
  const void* be2 = d_in[12];
  char* ws = (char*)d_ws;

  float* stats1   = (float*)(ws + O_STATS1);
  float* stats2   = (float*)(ws + O_STATS2);
  float* deg      = (float*)(ws + O_DEG);
  int*   cnt      = (int*)(ws + O_CNT);
  float* dinv     = (float*)(ws + O_DINV);
  int*   rowstart = (int*)(ws + O_ROWSTART);
  int*   fillpos  = (int*)(ws + O_FILL);
  float* bnp1     = (float*)(ws + O_BNP1);
  float* bnp2     = (float*)(ws + O_BNP2);
  int*   flag     = (int*)(ws + O_FLAG);
  int2*  csr      = (int2*)(ws + O_CSR);
  unsigned short* big = (unsigned short*)(ws + O_BIG);

  /* scratch ping-pong (always bf16): y1 = d_out[0:67MB], hlin = big,
     g2in = d_out, y2 = big, final overwrites d_out in the detected dtype */
  unsigned short* scr = (unsigned short*)d_out;

  STGCNBlock_90417651516131_kernel<<<1, 64, 0, stream>>>();
  stg_zero<<<40, 256, 0, stream>>>((float*)ws);
  stg_detect<<<1, 256, 0, stream>>>(x, flag);
  stg_conv<<<131072, 256, 0, stream>>>(x, 1, w1, b1, scr, stats1, flag);
  stg_deg<<<68, 256, 0, stream>>>(ei, ew, deg, cnt, flag);
  stg_bnparam<<<1, 64, 0, stream>>>(stats1, g1, be1, bnp1, flag);
  stg_scan<<<1, 1024, 0, stream>>>(deg, dinv, cnt, rowstart, fillpos);
  stg_fill<<<68, 256, 0, stream>>>(ei, ew, dinv, fillpos, csr, flag);
  stg_linear<<<131072, 256, 0, stream>>>(scr, bnp1, gw, big, flag);
  stg_agg<<<131072, 256, 0, stream>>>(big, csr, rowstart, gb, scr, flag);
  stg_conv<<<131072, 256, 0, stream>>>(scr, 0, w2, b2, big, stats2, flag);
  stg_bnparam<<<1, 64, 0, stream>>>(stats2, g2, be2, bnp2, flag);
  stg_final<<<131072, 256, 0, stream>>>(big, bnp2, x, d_out, flag);
}